// Round 6
// baseline (115.216 us; speedup 1.0000x reference)
//
#include <hip/hip_runtime.h>

#define Bn 4
#define Qn 1024
#define Kn 1024
#define Dd 256
#define Hh 64
#define Dv 256
#define TQ 16

typedef __attribute__((ext_vector_type(8))) short short8;
typedef __attribute__((ext_vector_type(8))) _Float16 half8;
typedef __attribute__((ext_vector_type(4))) float floatx4;
typedef __attribute__((ext_vector_type(2))) float floatx2;

__device__ __forceinline__ floatx2 fma2(floatx2 a, floatx2 b, floatx2 c) {
    return __builtin_elementwise_fma(a, b, c);
}
__device__ __forceinline__ floatx2 mk2(float x, float y) {
    floatx2 r; r.x = x; r.y = y; return r;
}

__device__ __forceinline__ short f32_to_bf16(float x) {
    unsigned u = __float_as_uint(x);
    unsigned r = u + 0x7fffu + ((u >> 16) & 1u);   // RNE
    return (short)(r >> 16);
}
__device__ __forceinline__ float bf16_to_f32(short h) {
    return __uint_as_float(((unsigned)(unsigned short)h) << 16);
}

// Fused prep v8: kt-streamed proj pipeline. R23 theory: v7 held X(64) +
// Wraw(64) + 4 frag arrays(128) all live -> >256 VGPR -> scratch spills,
// which explains 25us for ~1us of issue work. v8 double-buffers one
// kt-stage ({2 b128 X + 8 scalar W} = ~24 regs/stage), prefetches kt+1 at
// iteration top, consumes kt with cvt + 3 MFMA (~400 cyc cover for L2
// latency). MFMA order unchanged -> bit-identical results.
//  blocks 0..511  : proj (side=blk>>8, row-tile=(blk&255)*16, wave ct)
//  blocks 512..639: V -> fp16 A-frag swizzle (unchanged)
__global__ __launch_bounds__(256) void prep_kernel(const float* __restrict__ Xq,
                                                   const float* __restrict__ Wq,
                                                   const float* __restrict__ Xk,
                                                   const float* __restrict__ Wk,
                                                   const float* __restrict__ V,
                                                   float* __restrict__ Eq,
                                                   float* __restrict__ Ekt,
                                                   _Float16* __restrict__ Vh) {
    int t = threadIdx.x;
    int wave = t >> 6, l = t & 63;
    if (blockIdx.x < 512) {
        int side = blockIdx.x >> 8;              // 0: q, 1: k
        int r0 = (blockIdx.x & 255) * 16;        // row tile within side
        int ct = wave;                           // 16-col slice of H
        const float* X = side ? Xk : Xq;
        const float* W = side ? Wk : Wq;
        const float* xrow = X + (size_t)(r0 + (l & 15)) * Dd + (l >> 4) * 8;
        const float* wcol = W + (size_t)((l >> 4) * 8) * Hh + ct * 16 + (l & 15);

        floatx4 sxa[2], sxb[2];
        float swr[2][8];
#define PLOAD(kt, s) do {                                                   \
            sxa[s] = *(const floatx4*)(xrow + (kt) * 32);                   \
            sxb[s] = *(const floatx4*)(xrow + (kt) * 32 + 4);               \
            _Pragma("unroll")                                               \
            for (int j = 0; j < 8; ++j)                                     \
                swr[s][j] = wcol[(size_t)((kt) * 32 + j) * Hh];             \
        } while (0)

        PLOAD(0, 0);
        floatx4 acc = {0.f, 0.f, 0.f, 0.f};
        #pragma unroll
        for (int kt = 0; kt < 8; ++kt) {
            int cur = kt & 1;
            if (kt < 7) PLOAD(kt + 1, 1 - cur);   // prefetch next stage
            short8 ah, al, wh, wl;
            #pragma unroll
            for (int j = 0; j < 4; ++j) {
                short hs = f32_to_bf16(sxa[cur][j]);
                ah[j] = hs;
                al[j] = f32_to_bf16(sxa[cur][j] - bf16_to_f32(hs));
                short hs2 = f32_to_bf16(sxb[cur][j]);
                ah[j + 4] = hs2;
                al[j + 4] = f32_to_bf16(sxb[cur][j] - bf16_to_f32(hs2));
            }
            #pragma unroll
            for (int j = 0; j < 8; ++j) {
                short hs = f32_to_bf16(swr[cur][j]);
                wh[j] = hs;
                wl[j] = f32_to_bf16(swr[cur][j] - bf16_to_f32(hs));
            }
            acc = __builtin_amdgcn_mfma_f32_16x16x32_bf16(ah, wh, acc, 0, 0, 0);
            acc = __builtin_amdgcn_mfma_f32_16x16x32_bf16(al, wh, acc, 0, 0, 0);
            acc = __builtin_amdgcn_mfma_f32_16x16x32_bf16(ah, wl, acc, 0, 0, 0);
        }
#undef PLOAD
        // ---- epilogue: exp-fold and store ----
        int h = ct * 16 + (l & 15);
        float e0 = __expf(2.f * acc[0]);
        float e1 = __expf(2.f * acc[1]);
        float e2 = __expf(2.f * acc[2]);
        float e3 = __expf(2.f * acc[3]);
        int row0g = r0 + (l >> 4) * 4;           // reg i -> consecutive rows
        if (!side) {
            Eq[(size_t)(row0g + 0) * Hh + h] = e0;
            Eq[(size_t)(row0g + 1) * Hh + h] = e1;
            Eq[(size_t)(row0g + 2) * Hh + h] = e2;
            Eq[(size_t)(row0g + 3) * Hh + h] = e3;
        } else {
            int b = row0g >> 10, k0 = row0g & 1023;
            float4 o = { e0, e1, e2, e3 };
            *(float4*)(Ekt + ((size_t)(b * Hh + h)) * Kn + k0) = o;  // 16 full lines/instr
        }
    } else {
        int vblk = blockIdx.x - 512;
        int b = vblk >> 5;
        int kt = vblk & 31;
        const float* Vg = V + ((size_t)(b * Kn + kt * 32 + (l >> 4) * 8)) * Dv + (l & 15);
        #pragma unroll
        for (int p = 0; p < 4; ++p) {
            int nt = wave * 4 + p;
            const float* vp = Vg + nt * 16;
            half8 hv;
            #pragma unroll
            for (int j = 0; j < 8; ++j)
                hv[j] = (_Float16)vp[(size_t)j * Dv];
            size_t base = (((size_t)(b * 32 + kt) * 16 + nt) * 512) + (size_t)l * 8;
            *(half8*)(Vh + base) = hv;
        }
    }
}

// score(q,k) = W_sum - 2*sum_h w_h/(Eq_h*Ek_h+1); W_sum cancels in softmax.
// R23: q reads moved from per-wave s_load streams to a 4KB LDS stage.
// Theory: the scalar unit is per-CU and all 16 waves issued the SAME
// 17 s_load_dwordx4 per h4-iter (272 SMEM ops/CU/iter) -> scalar-pipe
// congestion + lgkmcnt chains were the score-phase stall. Wave-uniform
// ds_read_b128 broadcasts from LDS use the otherwise-idle DS pipe.
// Values bit-identical. TQ=16, grid 256, 1 block/CU.
__global__ __launch_bounds__(1024, 4) void attn_kernel(const float* __restrict__ Eq,
                                                       const float* __restrict__ Ekt,
                                                       const _Float16* __restrict__ Vh,
                                                       const float* __restrict__ wv,
                                                       float* __restrict__ out) {
    __shared__ __align__(16) unsigned sc[TQ * 1028];   // 65.8 KB: P hi/lo fp16
    __shared__ __align__(16) float qlds[TQ * Hh];      // 4 KB: Eq tile
    __shared__ float wsum[16 * TQ];

    int tid = threadIdx.x;
    int blk = blockIdx.x;
    // XCD swizzle: blk%8 = XCD; batch b pinned to XCDs {2b,2b+1}.
    int b = (blk & 7) >> 1;
    int tile = (blk >> 3) * 2 + (blk & 1);   // 0..63, bijective per batch
    int qbase = tile * TQ;

    // ---- stage Eq tile to LDS (coalesced, once) ----
    const float* qp = Eq + (size_t)(b * Qn + qbase) * Hh;
    qlds[tid] = qp[tid];
    __syncthreads();

    // ---- score phase: thread owns k = tid; q-pairs packed as float2 ----
    const float* kb = Ekt + (size_t)b * Hh * Kn;
    const float4* wv4 = (const float4*)wv;
    floatx2 s2[TQ / 2];
    #pragma unroll
    for (int i = 0; i < TQ / 2; ++i) { s2[i].x = 0.f; s2[i].y = 0.f; }

    float e0 = kb[0 * Kn + tid];
    float e1 = kb[1 * Kn + tid];
    float e2 = kb[2 * Kn + tid];
    float e3 = kb[3 * Kn + tid];
    floatx2 one2 = mk2(1.f, 1.f);
    for (int h4 = 0; h4 < Hh / 4; ++h4) {
        float n0, n1, n2, n3;
        if (h4 < Hh / 4 - 1) {                 // prefetch next iteration
            const float* kn = kb + (h4 + 1) * 4 * Kn;
            n0 = kn[0 * Kn + tid];
            n1 = kn[1 * Kn + tid];
            n2 = kn[2 * Kn + tid];
            n3 = kn[3 * Kn + tid];
        }
        float4 w4 = wv4[h4];                            // uniform -> s_load
        floatx2 e0s = mk2(e0, e0), e1s = mk2(e1, e1);
        floatx2 e2s = mk2(e2, e2), e3s = mk2(e3, e3);
        floatx2 wx = mk2(w4.x, w4.x), wy = mk2(w4.y, w4.y);
        floatx2 wz = mk2(w4.z, w4.z), ww = mk2(w4.w, w4.w);
        #pragma unroll
        for (int qq = 0; qq < TQ; qq += 2) {
            float4 qva = *(const float4*)(&qlds[qq * Hh + h4 * 4]);        // ds broadcast
            float4 qvb = *(const float4*)(&qlds[(qq + 1) * Hh + h4 * 4]);  // ds broadcast
            floatx2 A = fma2(mk2(qva.x, qvb.x), e0s, one2);
            floatx2 B = fma2(mk2(qva.y, qvb.y), e1s, one2);
            floatx2 C = fma2(mk2(qva.z, qvb.z), e2s, one2);
            floatx2 D = fma2(mk2(qva.w, qvb.w), e3s, one2);
            floatx2 AB = A * B;
            floatx2 CD = C * D;
            floatx2 ABCD = AB * CD;
            floatx2 NAB = fma2(wx, B, wy * A);
            floatx2 NCD = fma2(wz, D, ww * C);
            floatx2 NUM = fma2(NCD, AB, NAB * CD);
            floatx2 R = mk2(__builtin_amdgcn_rcpf(ABCD.x),
                            __builtin_amdgcn_rcpf(ABCD.y));
            s2[qq >> 1] = fma2(NUM, R, s2[qq >> 1]);
        }
        e0 = n0; e1 = n1; e2 = n2; e3 = n3;
    }

    int wave = tid >> 6, lane = tid & 63;
    // ---- V prefetch for kt=0: P-independent, hides under exp/pack/barrier ----
    size_t vb0 = (((size_t)(b * 32) * 16 + wave) * 512) + (size_t)lane * 8;
    half8 vcur = *(const half8*)(Vh + vb0);

    // p = exp(-2s); write fp16 hi/lo; per-q wave partials (fp32 p).
    _Float16* sp = (_Float16*)sc;
    float part[TQ];
    #pragma unroll
    for (int q = 0; q < TQ; ++q) {
        float sq = (q & 1) ? s2[q >> 1].y : s2[q >> 1].x;
        float p = __expf(-2.f * sq);
        part[q] = p;
        _Float16 hs = (_Float16)p;
        sp[q * 2056 + tid] = hs;
        sp[q * 2056 + 1024 + tid] = (_Float16)(p - (float)hs);
    }

    #pragma unroll
    for (int q = 0; q < TQ; ++q) {
        #pragma unroll
        for (int off = 32; off >= 1; off >>= 1)
            part[q] += __shfl_xor(part[q], off, 64);
    }
    if (lane == 0) {
        #pragma unroll
        for (int q = 0; q < TQ; ++q) wsum[wave * TQ + q] = part[q];
    }
    __syncthreads();

    // ---- AV via fp16 MFMA, software-pipelined V; wave owns ntile = wave ----
    int qf = lane & 15, kc = lane >> 4;
    floatx4 acc = {0.f, 0.f, 0.f, 0.f};
    const char* scb = (const char*)sc + qf * 4112 + kc * 16;
    #pragma unroll 2
    for (int kt = 0; kt < 31; ++kt) {
        half8 vnext = *(const half8*)(Vh + vb0 + (size_t)(kt + 1) * 8192);
        half8 bhi = *(const half8*)(scb + kt * 64);
        half8 blo = *(const half8*)(scb + 2048 + kt * 64);
        acc = __builtin_amdgcn_mfma_f32_16x16x32_f16(vcur, bhi, acc, 0, 0, 0);
        acc = __builtin_amdgcn_mfma_f32_16x16x32_f16(vcur, blo, acc, 0, 0, 0);
        vcur = vnext;
    }
    {
        half8 bhi = *(const half8*)(scb + 31 * 64);
        half8 blo = *(const half8*)(scb + 2048 + 31 * 64);
        acc = __builtin_amdgcn_mfma_f32_16x16x32_f16(vcur, bhi, acc, 0, 0, 0);
        acc = __builtin_amdgcn_mfma_f32_16x16x32_f16(vcur, blo, acc, 0, 0, 0);
    }
    {
        float vsum = 0.f;
        #pragma unroll
        for (int w = 0; w < 16; ++w) vsum += wsum[w * TQ + qf];
        float r = 1.f / vsum;
        float* ob = out + ((size_t)(b * Qn + qbase + qf)) * Dv + wave * 16 + kc * 4;
        float4 o = { acc[0] * r, acc[1] * r, acc[2] * r, acc[3] * r };
        *(float4*)ob = o;
    }
}

extern "C" void kernel_launch(void* const* d_in, const int* in_sizes, int n_in,
                              void* d_out, int out_size, void* d_ws, size_t ws_size,
                              hipStream_t stream) {
    const float* queries = (const float*)d_in[0];
    const float* keys    = (const float*)d_in[1];
    const float* values  = (const float*)d_in[2];
    const float* W_q     = (const float*)d_in[3];
    const float* W_k     = (const float*)d_in[4];
    const float* w_v     = (const float*)d_in[5];
    float* out = (float*)d_out;

    float* Eq  = (float*)d_ws;                    // [B*Q, H]      1 MB
    float* Ekt = Eq + Bn * Qn * Hh;               // [B, H, K]     1 MB
    _Float16* Vh = (_Float16*)(Ekt + Bn * Kn * Hh); // frag-order  2 MB

    prep_kernel<<<640, 256, 0, stream>>>(queries, W_q, keys, W_k, values,
                                         Eq, Ekt, Vh);
    attn_kernel<<<Bn * (Qn / TQ), 1024, 0, stream>>>(Eq, Ekt, Vh, w_v, out);
}